// Round 17
// baseline (97.028 us; speedup 1.0000x reference)
//
#include <hip/hip_runtime.h>
#include <hip/hip_bf16.h>

typedef __attribute__((ext_vector_type(8))) short bf16x8;
typedef __attribute__((ext_vector_type(4))) float f32x4;
typedef unsigned int u32;
typedef unsigned short u16;

#define NPOS 147456
#define NTILES 9216        // one 16-pos tile per block; grid = 9216

__device__ inline u16 bfc(float f) {
  union { __hip_bfloat16 h; u16 s; } u;
  u.h = __float2bfloat16(f);
  return u.s;
}

typedef const __attribute__((address_space(1))) u32 gas_u32;
typedef __attribute__((address_space(3))) u32 las_u32;

#define WAITVM0   asm volatile("s_waitcnt vmcnt(0)" ::: "memory")
#define SBAR      __builtin_amdgcn_s_barrier()
#define SCHB      __builtin_amdgcn_sched_barrier(0)
#define WAITLGKM  asm volatile("s_waitcnt lgkmcnt(0)" ::: "memory")

// ---------------------------------------------------------------------------
// CHURN DESIGN: 9216 blocks x 4 waves (wave h = head h); each block stages,
// computes, stores ONE tile and exits. Continuous memory pressure comes from
// the HW scheduler back-filling retiring blocks (naturally phase-staggered)
// instead of an in-block prefetch ladder (which convoy-phase-locks).
// LDS 26 KB: inbuf 24 KB (q 8K + tpr 16K, XOR-swizzled) + wvsh 2K.
// Two barriers total; single vmcnt(0) (nothing to keep in flight after it —
// the next tile belongs to another block).
// Weight frags gathered per-lane from raw f32 (L2-hot, 96 loads) UNDER the
// DMA wait. Body math identical to R9/R16 (verified).
// ---------------------------------------------------------------------------
__global__ __launch_bounds__(256) void tpa_kernel(
    const float* __restrict__ qe, const float* __restrict__ tpr,
    const float* __restrict__ tmk_p, const float* __restrict__ wq,
    const float* __restrict__ wk, const float* __restrict__ wv,
    const float* __restrict__ wo, const float* __restrict__ ob,
    float* __restrict__ out)
{
  __shared__ int4 inbuf4[1536];  // 24 KB: [0,8K) qe rows, [8K,24K) tpr
  __shared__ u32 wvsh32[512];    // 2 KB WV exchange
  char* const inb  = (char*)inbuf4;
  char* const wvsh = (char*)wvsh32;

  const int tid = threadIdx.x;
  const int wid = tid >> 6;           // wave id = head h
  const int lane = tid & 63;
  const int l15 = lane & 15, g = lane >> 4;
  const int swz = (l15 & 7) << 4;
  const int h = wid;
  const int p0 = blockIdx.x * 16;

  // ---- issue this tile's 6 DMAs immediately (R6-verified layout) ----
  // chunk m = (wid + 4*j)*64 + lane in [0,1536): m<512 -> qe, else tpr
  SCHB;
  #pragma unroll
  for (int j = 0; j < 6; ++j) {
    int m = (wid + 4 * j) * 64 + lane;
    const char* s_;
    if (m < 512) {                               // qe region: 8 KB
      int pos = m >> 5, inner = ((m & 31) * 16) ^ ((pos & 7) << 4);
      s_ = (const char*)qe + ((size_t)(p0 + pos)) * 512 + inner;
    } else {                                     // tpr region: 16 KB
      int m2 = m - 512, t = m2 >> 8, pos = (m2 >> 4) & 15;
      int inner = ((m2 & 15) * 16) ^ ((pos & 7) << 4);
      s_ = (const char*)tpr + ((size_t)t * NPOS + p0 + pos) * 256 + inner;
    }
    char* d_ = inb + (wid + 4 * j) * 1024;
    __builtin_amdgcn_global_load_lds((gas_u32*)s_, (las_u32*)d_, 16, 0, 0);
  }
  SCHB;

  // ---- weight fragment gather (R16-verified), flies under the DMA wait ----
  bf16x8 wqf[4], wkf[2], wvf[2], wof[2][2];
  #pragma unroll
  for (int kc = 0; kc < 4; ++kc)
    #pragma unroll
    for (int e = 0; e < 8; ++e) {
      int c = kc * 32 + g * 8 + e;
      wqf[kc][e] = (short)bfc(wq[h * 2048 + c * 16 + l15] * 0.25f);  // fold D^-0.5
    }
  SCHB;   // chunk boundary: cap transient f32 staging regs
  #pragma unroll
  for (int kc = 0; kc < 2; ++kc)
    #pragma unroll
    for (int e = 0; e < 8; ++e) {
      int c = kc * 32 + g * 8 + e;
      wkf[kc][e] = (short)bfc(wk[h * 1024 + c * 16 + l15]);
      wvf[kc][e] = (short)bfc(wv[h * 1024 + c * 16 + l15]);
    }
  SCHB;
  #pragma unroll
  for (int j = 0; j < 2; ++j)
    #pragma unroll
    for (int kc = 0; kc < 2; ++kc)
      #pragma unroll
      for (int e = 0; e < 8; ++e) {
        int hd = kc * 32 + g * 8 + e;
        wof[j][kc][e] = (short)bfc(wo[(hd >> 4) * 2048 + (hd & 15) * 128 +
                                      (2 * h + j) * 16 + l15]);
      }
  SCHB;

  const float m0 = tmk_p[0], m1 = tmk_p[1], m2 = tmk_p[2], m3 = tmk_p[3];
  const float biasv[4] = {65504.0f * (m0 - 1.0f), 65504.0f * (m1 - 1.0f),
                          65504.0f * (m2 - 1.0f), 65504.0f * (m3 - 1.0f)};
  const float tmk = (m0 + m1 + m2 + m3 > 0.0f) ? 1.0f : 0.0f;

  f32x4 obf[2];
  {
    const f32x4* obase = reinterpret_cast<const f32x4*>(ob);
    #pragma unroll
    for (int j = 0; j < 2; ++j) {
      const f32x4 o = obase[(2 * h + j) * 4 + g];
      #pragma unroll
      for (int r = 0; r < 4; ++r) obf[j][r] = o[r] * tmk;
    }
  }

  // ---- barrier 1: all DMAs (and gather) complete ----
  SCHB; WAITVM0; SBAR; SCHB;

  // ---- qGEMM (swapped): qT = Q^T, lane = [d=g*4+r][pos=l15] ----
  f32x4 qT = (f32x4){0.f, 0.f, 0.f, 0.f};
  {
    const char* qrow = inb + l15 * 512;
    #pragma unroll
    for (int kc = 0; kc < 4; ++kc) {
      const int cb = kc * 128 + g * 32;
      f32x4 lo = *(const f32x4*)(qrow + ((cb) ^ swz));
      f32x4 hi = *(const f32x4*)(qrow + ((cb + 16) ^ swz));
      bf16x8 aq;
      #pragma unroll
      for (int e = 0; e < 4; ++e) { aq[e] = (short)bfc(lo[e]); aq[e + 4] = (short)bfc(hi[e]); }
      qT = __builtin_amdgcn_mfma_f32_16x16x32_bf16(wqf[kc], aq, qT, 0, 0, 0);
    }
  }

  // ---- 4 template steps: K/V proj + no-max softmax accumulate ----
  float ssum = 0.f;
  f32x4 wvT = (f32x4){0.f, 0.f, 0.f, 0.f};
  #pragma unroll
  for (int t = 0; t < 4; ++t) {
    const char* trow = inb + 8192 + t * 4096 + l15 * 256;
    bf16x8 at0, at1;
    { f32x4 lo = *(const f32x4*)(trow + ((g * 32) ^ swz));
      f32x4 hi = *(const f32x4*)(trow + ((g * 32 + 16) ^ swz));
      #pragma unroll
      for (int e = 0; e < 4; ++e) { at0[e] = (short)bfc(lo[e]); at0[e + 4] = (short)bfc(hi[e]); } }
    { f32x4 lo = *(const f32x4*)(trow + ((128 + g * 32) ^ swz));
      f32x4 hi = *(const f32x4*)(trow + ((128 + g * 32 + 16) ^ swz));
      #pragma unroll
      for (int e = 0; e < 4; ++e) { at1[e] = (short)bfc(lo[e]); at1[e + 4] = (short)bfc(hi[e]); } }
    f32x4 kT = (f32x4){0.f, 0.f, 0.f, 0.f};
    f32x4 vT = (f32x4){0.f, 0.f, 0.f, 0.f};
    kT = __builtin_amdgcn_mfma_f32_16x16x32_bf16(wkf[0], at0, kT, 0, 0, 0);
    kT = __builtin_amdgcn_mfma_f32_16x16x32_bf16(wkf[1], at1, kT, 0, 0, 0);
    vT = __builtin_amdgcn_mfma_f32_16x16x32_bf16(wvf[0], at0, vT, 0, 0, 0);
    vT = __builtin_amdgcn_mfma_f32_16x16x32_bf16(wvf[1], at1, vT, 0, 0, 0);
    float lg = qT[0] * kT[0] + qT[1] * kT[1] + qT[2] * kT[2] + qT[3] * kT[3];
    lg += __shfl_xor(lg, 16);
    lg += __shfl_xor(lg, 32);
    const float w = __expf(lg + biasv[t]);
    ssum += w;
    #pragma unroll
    for (int r = 0; r < 4; ++r) wvT[r] += w * vT[r];
  }

  // ---- normalize + pack into exchange buffer ----
  {
    const float inv = tmk / fmaxf(ssum, 1e-30f);
    u32 pk0 = (u32)bfc(wvT[0] * inv) | ((u32)bfc(wvT[1] * inv) << 16);
    u32 pk1 = (u32)bfc(wvT[2] * inv) | ((u32)bfc(wvT[3] * inv) << 16);
    const int hb = h * 32 + g * 8;
    *(u32*)(wvsh + ((l15 * 128 + hb) ^ swz))     = pk0;
    *(u32*)(wvsh + ((l15 * 128 + hb + 4) ^ swz)) = pk1;
  }

  // ---- barrier 2: exchange visible ----
  SCHB; WAITLGKM; SBAR; SCHB;

  // ---- out-projection + store ----
  {
    bf16x8 bwv0 = *(const bf16x8*)(wvsh + ((l15 * 128 + g * 16)      ^ swz));
    bf16x8 bwv1 = *(const bf16x8*)(wvsh + ((l15 * 128 + 64 + g * 16) ^ swz));
    #pragma unroll
    for (int j = 0; j < 2; ++j) {
      f32x4 acc = (f32x4){0.f, 0.f, 0.f, 0.f};
      acc = __builtin_amdgcn_mfma_f32_16x16x32_bf16(wof[j][0], bwv0, acc, 0, 0, 0);
      acc = __builtin_amdgcn_mfma_f32_16x16x32_bf16(wof[j][1], bwv1, acc, 0, 0, 0);
      f32x4 res;
      #pragma unroll
      for (int r = 0; r < 4; ++r) res[r] = acc[r] + obf[j][r];
      *(f32x4*)(out + (size_t)(p0 + l15) * 128 + (2 * h + j) * 16 + g * 4) = res;
    }
  }
}

extern "C" void kernel_launch(void* const* d_in, const int* in_sizes, int n_in,
                              void* d_out, int out_size, void* d_ws, size_t ws_size,
                              hipStream_t stream) {
  const float* qe  = (const float*)d_in[0];
  const float* tpr = (const float*)d_in[1];
  const float* tmk = (const float*)d_in[2];
  const float* wq  = (const float*)d_in[3];
  const float* wk  = (const float*)d_in[4];
  const float* wv  = (const float*)d_in[5];
  const float* wo  = (const float*)d_in[6];
  const float* ob  = (const float*)d_in[7];
  float* out = (float*)d_out;

  tpa_kernel<<<NTILES, 256, 0, stream>>>(qe, tpr, tmk, wq, wk, wv, wo, ob, out);
}